// Round 5
// baseline (278.760 us; speedup 1.0000x reference)
//
#include <hip/hip_runtime.h>
#include <hip/hip_bf16.h>

// CosineLoss: out = mean_i( 1 - dot(a_i,b_i) / (||a_i||*||b_i||) )
// inputs: d_in[0]=cxr (N,D) f32, d_in[1]=ehr (N,D) f32; N=16384, D=2048.
//
// R4 lesson: compact sliding window gave the SAME ~2.8 TB/s delivered as
// scattered wave-per-row -> plateau is concurrency-limited, not page
// locality. All prior rounds ran ~16 waves/CU with ~2 KB in flight each.
// Now: 32 waves/CU (launch_bounds(256,8), VGPR<=64, grid exactly resident),
// each wave streams 2 contiguous rows with a depth-2 named-variable
// pipeline (no runtime-indexed arrays -> no scratch spill), reduction
// overlapped with the next row's in-flight loads.

#define ROWS 16384
#define COLS_V4 512               // float4 per row (D=2048)
#define BLOCK 256
#define GRID 2048                 // 8 blocks/CU * 256 CU, all resident
#define WPB (BLOCK / 64)          // 4 waves per block
#define RPW 2                     // rows per wave: 2048*4*2 = 16384
#define CHUNKS (COLS_V4 / 64)     // 8 chunk-steps per row
#define TOTAL_S (RPW * CHUNKS)    // 16 flattened steps per wave

__global__ __launch_bounds__(BLOCK, 8) void cosine_partial_kernel(
    const float4* __restrict__ A,
    const float4* __restrict__ B,
    float* __restrict__ partial) {
    const int wave = threadIdx.x >> 6;
    const int lane = threadIdx.x & 63;
    const int wid  = blockIdx.x * WPB + wave;      // 0..8191
    const size_t row0 = (size_t)wid * RPW;

    // Lane walks 2 consecutive rows contiguously: step s reads vec4
    // [row0*512 + s*64 + lane] — rows are adjacent so it's one 16 KB stream.
    const float4* __restrict__ a = A + row0 * COLS_V4 + lane;
    const float4* __restrict__ b = B + row0 * COLS_V4 + lane;

    float4 x = a[0];
    float4 y = b[0];
    float dot = 0.f, aa = 0.f, bb = 0.f;
    float losses = 0.f;

    #pragma unroll
    for (int s = 0; s < TOTAL_S; ++s) {
        float4 xn, yn;
        if (s + 1 < TOTAL_S) {
            xn = a[(s + 1) * 64];
            yn = b[(s + 1) * 64];
        }
        dot += x.x * y.x + x.y * y.y + x.z * y.z + x.w * y.w;
        aa  += x.x * x.x + x.y * x.y + x.z * x.z + x.w * x.w;
        bb  += y.x * y.y * 0.f + y.x * y.x + y.y * y.y + y.z * y.z + y.w * y.w;
        if ((s & (CHUNKS - 1)) == (CHUNKS - 1)) {
            // end of a row: wave-reduce while next row's loads are in flight
            float d = dot, p = aa, q = bb;
            #pragma unroll
            for (int off = 32; off > 0; off >>= 1) {
                d += __shfl_down(d, off, 64);
                p += __shfl_down(p, off, 64);
                q += __shfl_down(q, off, 64);
            }
            if (lane == 0) losses += 1.0f - d * rsqrtf(p * q);
            dot = 0.f; aa = 0.f; bb = 0.f;
        }
        x = xn;
        y = yn;
    }

    __shared__ float s_loss[WPB];
    if (lane == 0) s_loss[wave] = losses;
    __syncthreads();
    if (threadIdx.x == 0) {
        partial[blockIdx.x] = s_loss[0] + s_loss[1] + s_loss[2] + s_loss[3];
    }
}

__global__ __launch_bounds__(256) void cosine_reduce_kernel(
    const float* __restrict__ partial,
    float* __restrict__ out) {
    const int t = threadIdx.x;
    float s = 0.f;
    #pragma unroll
    for (int i = 0; i < GRID / 256; ++i) s += partial[t + i * 256];
    #pragma unroll
    for (int off = 32; off > 0; off >>= 1) s += __shfl_down(s, off, 64);

    __shared__ float s_sum[4];
    const int wave = t >> 6;
    const int lane = t & 63;
    if (lane == 0) s_sum[wave] = s;
    __syncthreads();
    if (t == 0) {
        out[0] = (s_sum[0] + s_sum[1] + s_sum[2] + s_sum[3]) * (1.0f / (float)ROWS);
    }
}

extern "C" void kernel_launch(void* const* d_in, const int* in_sizes, int n_in,
                              void* d_out, int out_size, void* d_ws, size_t ws_size,
                              hipStream_t stream) {
    const float4* cxr = (const float4*)d_in[0];
    const float4* ehr = (const float4*)d_in[1];
    float* out     = (float*)d_out;
    float* partial = (float*)d_ws;   // GRID floats = 8 KB, fully overwritten

    cosine_partial_kernel<<<GRID, BLOCK, 0, stream>>>(cxr, ehr, partial);
    cosine_reduce_kernel<<<1, 256, 0, stream>>>(partial, out);
}